// Round 2
// baseline (541.764 us; speedup 1.0000x reference)
//
#include <hip/hip_runtime.h>
#include <math.h>

#define NUSER 2560
#define NITEM 3584
#define NN    6144
#define EDIM  64
#define NNZ   200000
#define DQK   256
#define KTOP  5
#define SPLITS 12
#define TPS    4          // 128-wide cand tiles per split (48/12)
#define TPB   256

// ---------------------------------------------------------------- utility
__global__ void zero_kernel(float4* __restrict__ p, int n4) {
    int i = blockIdx.x * TPB + threadIdx.x;
    if (i < n4) p[i] = make_float4(0.f, 0.f, 0.f, 0.f);
}

// ---------------------------------------------------------------- CSR build: hist -> scan -> scatter
__global__ void hist_kernel(const int* __restrict__ nr, const int* __restrict__ ar,
                            int* __restrict__ cnt_n, int* __restrict__ cnt_a) {
    int g = blockIdx.x * TPB + threadIdx.x;
    if (g < NNZ) atomicAdd(&cnt_n[nr[g]], 1);
    else if (g < 2 * NNZ) atomicAdd(&cnt_a[ar[g - NNZ]], 1);
}

__global__ void scan_kernel(const int* __restrict__ cnt_n, const int* __restrict__ cnt_a,
                            int* __restrict__ start_n, int* __restrict__ start_a,
                            int* __restrict__ cur_n, int* __restrict__ cur_a) {
    const int* cnt = blockIdx.x ? cnt_a : cnt_n;
    int* start = blockIdx.x ? start_a : start_n;
    int* cur   = blockIdx.x ? cur_a   : cur_n;
    __shared__ int sc[1024];
    int t = threadIdx.x;
    int loc[6]; int p = 0;
#pragma unroll
    for (int j = 0; j < 6; ++j) { loc[j] = cnt[t * 6 + j]; p += loc[j]; }
    sc[t] = p; __syncthreads();
    for (int off = 1; off < 1024; off <<= 1) {
        int v = (t >= off) ? sc[t - off] : 0;
        __syncthreads();
        sc[t] += v;
        __syncthreads();
    }
    int base = sc[t] - p;   // exclusive
#pragma unroll
    for (int j = 0; j < 6; ++j) { start[t * 6 + j] = base; cur[t * 6 + j] = base; base += loc[j]; }
    if (t == 1023) start[6144] = base;
}

__global__ void scatter_kernel(const int* __restrict__ nr, const int* __restrict__ nc,
                               const float* __restrict__ nv,
                               const int* __restrict__ ar, const int* __restrict__ ac,
                               const float* __restrict__ av,
                               int* __restrict__ cur_n, int* __restrict__ cur_a,
                               int2* __restrict__ cv_n, int2* __restrict__ cv_a) {
    int g = blockIdx.x * TPB + threadIdx.x;
    if (g < NNZ) {
        int pos = atomicAdd(&cur_n[nr[g]], 1);
        cv_n[pos] = make_int2(nc[g], __float_as_int(nv[g]));
    } else if (g < 2 * NNZ) {
        int h = g - NNZ;
        int pos = atomicAdd(&cur_a[ar[h]], 1);
        cv_a[pos] = make_int2(ac[h], __float_as_int(av[h]));
    }
}

// ---------------------------------------------------------------- CSR SpMM, wave-per-row, lanes = 64 dims
__global__ void spmm_csr_emb_kernel(const int* __restrict__ start, const int2* __restrict__ cv,
                                    const float* __restrict__ user, const float* __restrict__ item,
                                    float* __restrict__ dst) {
    int r = blockIdx.x * 4 + (threadIdx.x >> 6);
    int lane = threadIdx.x & 63;
    int s = start[r], e = start[r + 1];
    float acc = 0.f;
    for (int j = s; j < e; ++j) {
        int2 c = cv[j];
        float x = (c.x < NUSER) ? user[c.x * EDIM + lane] : item[(c.x - NUSER) * EDIM + lane];
        acc = fmaf(__int_as_float(c.y), x, acc);
    }
    dst[r * EDIM + lane] = acc;
}

__global__ void spmm_csr_kernel(const int* __restrict__ start, const int2* __restrict__ cv,
                                const float* __restrict__ src, float* __restrict__ dst) {
    int r = blockIdx.x * 4 + (threadIdx.x >> 6);
    int lane = threadIdx.x & 63;
    int s = start[r], e = start[r + 1];
    float acc = 0.f;
    for (int j = s; j < e; ++j) {
        int2 c = cv[j];
        acc = fmaf(__int_as_float(c.y), src[c.x * EDIM + lane], acc);
    }
    dst[r * EDIM + lane] = acc;
}

// Qm = ego2 + 0.5 * (A @ ego2) ; outmean = 0.5*(ego0 + ego1)
__global__ void qm_mean_kernel(const int* __restrict__ start, const int2* __restrict__ cv,
                               const float* __restrict__ ego2, const float* __restrict__ ego1,
                               const float* __restrict__ user, const float* __restrict__ item,
                               float* __restrict__ Qm, float* __restrict__ outmean) {
    int r = blockIdx.x * 4 + (threadIdx.x >> 6);
    int lane = threadIdx.x & 63;
    int s = start[r], e = start[r + 1];
    float acc = 0.f;
    for (int j = s; j < e; ++j) {
        int2 c = cv[j];
        acc = fmaf(__int_as_float(c.y), ego2[c.x * EDIM + lane], acc);
    }
    int o = r * EDIM + lane;
    Qm[o] = ego2[o] + 0.5f * acc;
    float e0 = (r < NUSER) ? user[o] : item[o - NUSER * EDIM];
    outmean[o] = 0.5f * (e0 + ego1[o]);
}

// ---------------------------------------------------------------- transpose ego2 [NN][64] -> PT [64][NN]
__global__ void transpose_kernel(const float* __restrict__ src, float* __restrict__ dst) {
    __shared__ float st[64][65];
    int t = threadIdx.x;
    int r0 = blockIdx.x * 64;
    {
        int r = t & 63, q = t >> 6;
#pragma unroll
        for (int rep = 0; rep < 4; ++rep) {
            int e = q * 16 + rep * 4;
            float4 v = *(const float4*)&src[(r0 + r) * EDIM + e];
            st[r][e + 0] = v.x; st[r][e + 1] = v.y; st[r][e + 2] = v.z; st[r][e + 3] = v.w;
        }
    }
    __syncthreads();
    {
        int tx = t & 15, e0 = t >> 4;
#pragma unroll
        for (int rep = 0; rep < 4; ++rep) {
            int e = e0 + rep * 16;
            float4 w = make_float4(st[tx * 4 + 0][e], st[tx * 4 + 1][e],
                                   st[tx * 4 + 2][e], st[tx * 4 + 3][e]);
            *(float4*)&dst[e * NN + r0 + tx * 4] = w;
        }
    }
}

// ---------------------------------------------------------------- QKV GEMM (unchanged, validated)
__global__ __launch_bounds__(TPB, 3) void qkv_gemm_kernel(
        const float* __restrict__ A,
        const float* __restrict__ Wq, const float* __restrict__ bq,
        const float* __restrict__ Wk, const float* __restrict__ bk,
        const float* __restrict__ Wv, const float* __restrict__ bv,
        float* __restrict__ Qa, float* __restrict__ Ka, float* __restrict__ Va) {
    const float* W; const float* b; float* out;
    if (blockIdx.z == 0)      { W = Wq; b = bq; out = Qa; }
    else if (blockIdx.z == 1) { W = Wk; b = bk; out = Ka; }
    else                      { W = Wv; b = bv; out = Va; }

    __shared__ __align__(16) float smem[64 * 64 + 128 * 64];
    float* As = smem;
    float* Bs = smem + 4096;
    int t = threadIdx.x, tx = t & 15, ty = t >> 4;
    int r0 = blockIdx.x * 64, d0 = blockIdx.y * 128;

    {
        int r = t & 63, eb = (t >> 6) * 16;
#pragma unroll
        for (int rep = 0; rep < 4; ++rep) {
            int e0 = eb + rep * 4;
            float4 v = *(const float4*)&A[(r0 + r) * EDIM + e0];
            As[(e0 + 0) * 64 + r] = v.x; As[(e0 + 1) * 64 + r] = v.y;
            As[(e0 + 2) * 64 + r] = v.z; As[(e0 + 3) * 64 + r] = v.w;
        }
    }
    {
        int d = t & 127, eb = (t >> 7) * 32;
#pragma unroll
        for (int rep = 0; rep < 8; ++rep) {
            int e0 = eb + rep * 4;
            float4 v = *(const float4*)&W[(d0 + d) * EDIM + e0];
            Bs[(e0 + 0) * 128 + d] = v.x; Bs[(e0 + 1) * 128 + d] = v.y;
            Bs[(e0 + 2) * 128 + d] = v.z; Bs[(e0 + 3) * 128 + d] = v.w;
        }
    }
    __syncthreads();

    float acc[4][8];
#pragma unroll
    for (int i = 0; i < 4; ++i)
#pragma unroll
        for (int j = 0; j < 8; ++j) acc[i][j] = 0.f;

#pragma unroll 4
    for (int e = 0; e < 64; ++e) {
        float4 a  = *(const float4*)&As[e * 64 + ty * 4];
        float4 b0 = *(const float4*)&Bs[e * 128 + tx * 4];
        float4 b1 = *(const float4*)&Bs[e * 128 + 64 + tx * 4];
        float ar[4] = {a.x, a.y, a.z, a.w};
#pragma unroll
        for (int i = 0; i < 4; ++i) {
            acc[i][0] = fmaf(ar[i], b0.x, acc[i][0]);
            acc[i][1] = fmaf(ar[i], b0.y, acc[i][1]);
            acc[i][2] = fmaf(ar[i], b0.z, acc[i][2]);
            acc[i][3] = fmaf(ar[i], b0.w, acc[i][3]);
            acc[i][4] = fmaf(ar[i], b1.x, acc[i][4]);
            acc[i][5] = fmaf(ar[i], b1.y, acc[i][5]);
            acc[i][6] = fmaf(ar[i], b1.z, acc[i][6]);
            acc[i][7] = fmaf(ar[i], b1.w, acc[i][7]);
        }
    }
    float4 bias0 = *(const float4*)&b[d0 + tx * 4];
    float4 bias1 = *(const float4*)&b[d0 + 64 + tx * 4];
#pragma unroll
    for (int i = 0; i < 4; ++i) {
        int r = r0 + ty * 4 + i;
        float4 o0 = make_float4(acc[i][0] + bias0.x, acc[i][1] + bias0.y,
                                acc[i][2] + bias0.z, acc[i][3] + bias0.w);
        float4 o1 = make_float4(acc[i][4] + bias1.x, acc[i][5] + bias1.y,
                                acc[i][6] + bias1.z, acc[i][7] + bias1.w);
        *(float4*)&out[r * DQK + d0 + tx * 4] = o0;
        *(float4*)&out[r * DQK + d0 + 64 + tx * 4] = o1;
    }
}

// ---------------------------------------------------------------- fused sim top-5
// 128 rows x (TPS x 128 cands) per block; Q in LDS [e][r]; P streamed from PT [e][c] global.
__device__ __forceinline__ void ins5(float v, int ci, float tv[KTOP], int ti[KTOP]) {
    if (v > tv[4]) {
#pragma unroll
        for (int k = 4; k >= 1; --k) {
            bool sh = v > tv[k];
            bool ph = v > tv[k - 1];
            float nv = ph ? tv[k - 1] : v;
            int   ni = ph ? ti[k - 1] : ci;
            if (sh) { tv[k] = nv; ti[k] = ni; }
        }
        if (v > tv[0]) { tv[0] = v; ti[0] = ci; }
    }
}

__global__ __launch_bounds__(TPB, 2) void topk_partial_kernel(
        const float* __restrict__ Qm, const float* __restrict__ PT,
        float* __restrict__ pval, int* __restrict__ pidx) {
    __shared__ __align__(16) float smem[64 * 81 * 2];   // staging uses 8192 floats; merge 10368
    float* Qs = smem;                                   // [e][r] stride 128
    int t = threadIdx.x, tx = t & 15, ty = t >> 4;
    int r0 = blockIdx.x * 128;
    int s  = blockIdx.y;

    { // stage Q transposed (once per block)
        int r = t & 127, e0 = (t >> 7) * 32;
#pragma unroll
        for (int rep = 0; rep < 8; ++rep) {
            int e = e0 + rep * 4;
            float4 v = *(const float4*)&Qm[(r0 + r) * EDIM + e];
            Qs[(e + 0) * 128 + r] = v.x;
            Qs[(e + 1) * 128 + r] = v.y;
            Qs[(e + 2) * 128 + r] = v.z;
            Qs[(e + 3) * 128 + r] = v.w;
        }
    }
    __syncthreads();

    float t5v[8][KTOP]; int t5i[8][KTOP];
#pragma unroll
    for (int i = 0; i < 8; ++i)
#pragma unroll
        for (int k = 0; k < KTOP; ++k) { t5v[i][k] = -INFINITY; t5i[i][k] = 0x7fffffff; }

    for (int tile = 0; tile < TPS; ++tile) {
        int c0 = (s * TPS + tile) * 128;
        const float* pb = PT + c0 + tx * 4;

        float acc[8][8];
#pragma unroll
        for (int i = 0; i < 8; ++i)
#pragma unroll
            for (int j = 0; j < 8; ++j) acc[i][j] = 0.f;

        // depth-2 software pipeline on the streamed B operand
        float4 c00 = *(const float4*)&pb[0 * NN];
        float4 c01 = *(const float4*)&pb[0 * NN + 64];
        float4 c10 = *(const float4*)&pb[1 * NN];
        float4 c11 = *(const float4*)&pb[1 * NN + 64];

        for (int e = 0; e < 64; e += 2) {
            float4 u0 = c00, u1 = c01, v0 = c10, v1 = c11;
            if (e + 2 < 64) {
                c00 = *(const float4*)&pb[(e + 2) * NN];
                c01 = *(const float4*)&pb[(e + 2) * NN + 64];
                c10 = *(const float4*)&pb[(e + 3) * NN];
                c11 = *(const float4*)&pb[(e + 3) * NN + 64];
            }
#pragma unroll
            for (int half = 0; half < 2; ++half) {
                int ee = e + half;
                float4 b0 = half ? v0 : u0;
                float4 b1 = half ? v1 : u1;
                float4 a0 = *(const float4*)&Qs[ee * 128 + ty * 4];
                float4 a1 = *(const float4*)&Qs[ee * 128 + 64 + ty * 4];
                float ar[8] = {a0.x, a0.y, a0.z, a0.w, a1.x, a1.y, a1.z, a1.w};
                float br[8] = {b0.x, b0.y, b0.z, b0.w, b1.x, b1.y, b1.z, b1.w};
#pragma unroll
                for (int i = 0; i < 8; ++i)
#pragma unroll
                    for (int j = 0; j < 8; ++j)
                        acc[i][j] = fmaf(ar[i], br[j], acc[i][j]);
            }
        }

        // top-5 update; candidate index increasing in j for tie semantics
#pragma unroll
        for (int i = 0; i < 8; ++i)
#pragma unroll
            for (int j = 0; j < 8; ++j) {
                int ci = c0 + (j >> 2) * 64 + tx * 4 + (j & 3);
                ins5(acc[i][j], ci, t5v[i], t5i[i]);
            }
    }

    // merge 16 per-thread lists per row, two row-groups of 64 (stride 81 kills conflicts)
    float* mv = smem;
    int*   mi = (int*)(smem + 64 * 81);
    for (int g = 0; g < 2; ++g) {
        __syncthreads();
#pragma unroll
        for (int i = 0; i < 4; ++i)
#pragma unroll
            for (int k = 0; k < KTOP; ++k) {
                mv[(ty * 4 + i) * 81 + tx * 5 + k] = t5v[g * 4 + i][k];
                mi[(ty * 4 + i) * 81 + tx * 5 + k] = t5i[g * 4 + i][k];
            }
        __syncthreads();
        if (t < 64) {
            float pvL = INFINITY; int piL = -1;
            for (int k = 0; k < KTOP; ++k) {
                float bv = -INFINITY; int bi = 0x7fffffff;
                for (int n = 0; n < 80; ++n) {
                    float v = mv[t * 81 + n];
                    int   x = mi[t * 81 + n];
                    bool worse_prev  = (v < pvL) || (v == pvL && x > piL);
                    bool better_best = (v > bv)  || (v == bv  && x < bi);
                    if (worse_prev && better_best) { bv = v; bi = x; }
                }
                int o = ((r0 + g * 64 + t) * SPLITS + s) * KTOP + k;
                pval[o] = bv; pidx[o] = bi;
                pvL = bv; piL = bi;
            }
        }
    }
}

// ---------------------------------------------------------------- final merge across splits
__global__ void topk_final_kernel(const float* __restrict__ pval, const int* __restrict__ pidx,
                                  int* __restrict__ idxout) {
    int r = blockIdx.x * TPB + threadIdx.x;
    const float* pv = pval + r * SPLITS * KTOP;
    const int*   pi = pidx + r * SPLITS * KTOP;
    float prevv = INFINITY; int previ = -1;
    for (int k = 0; k < KTOP; ++k) {
        float bv = -INFINITY; int bi = 0x7fffffff;
        for (int n = 0; n < SPLITS * KTOP; ++n) {
            float v = pv[n]; int x = pi[n];
            bool worse_prev  = (v < prevv) || (v == prevv && x > previ);
            bool better_best = (v > bv)    || (v == bv    && x < bi);
            if (worse_prev && better_best) { bv = v; bi = x; }
        }
        idxout[r * KTOP + k] = bi;
        prevv = bv; previ = bi;
    }
}

// ---------------------------------------------------------------- attention epilogue (one wave per row)
__global__ __launch_bounds__(TPB) void attn_kernel(
        const float* __restrict__ Qa, const float* __restrict__ Ka, const float* __restrict__ Va,
        const int* __restrict__ idx, float* __restrict__ out) {
    int wv = threadIdx.x >> 6, lane = threadIdx.x & 63;
    int r = blockIdx.x * 4 + wv;
    int cI[KTOP];
#pragma unroll
    for (int k = 0; k < KTOP; ++k) cI[k] = idx[r * KTOP + k];
    float4 q = *(const float4*)&Qa[r * DQK + lane * 4];
    float sc[KTOP];
#pragma unroll
    for (int k = 0; k < KTOP; ++k) {
        float4 kk = *(const float4*)&Ka[cI[k] * DQK + lane * 4];
        float p = q.x * kk.x + q.y * kk.y + q.z * kk.z + q.w * kk.w;
#pragma unroll
        for (int off = 32; off; off >>= 1) p += __shfl_xor(p, off, 64);
        sc[k] = p * 0.0625f;
    }
    float m = sc[0];
#pragma unroll
    for (int k = 1; k < KTOP; ++k) m = fmaxf(m, sc[k]);
    float w[KTOP], ssum = 0.f;
#pragma unroll
    for (int k = 0; k < KTOP; ++k) { w[k] = expf(sc[k] - m); ssum += w[k]; }
    float inv = 1.f / ssum;
    float4 o = make_float4(0.f, 0.f, 0.f, 0.f);
#pragma unroll
    for (int k = 0; k < KTOP; ++k) {
        float4 vv = *(const float4*)&Va[cI[k] * DQK + lane * 4];
        float a = w[k] * inv;
        o.x = fmaf(a, vv.x, o.x); o.y = fmaf(a, vv.y, o.y);
        o.z = fmaf(a, vv.z, o.z); o.w = fmaf(a, vv.w, o.w);
    }
    *(float4*)&out[r * DQK + lane * 4] = o;
}

// ---------------------------------------------------------------- launch
extern "C" void kernel_launch(void* const* d_in, const int* in_sizes, int n_in,
                              void* d_out, int out_size, void* d_ws, size_t ws_size,
                              hipStream_t stream) {
    const float* user  = (const float*)d_in[0];
    const float* item  = (const float*)d_in[1];
    const int*   nrows = (const int*)d_in[2];
    const int*   ncols = (const int*)d_in[3];
    const float* nvals = (const float*)d_in[4];
    const int*   arows = (const int*)d_in[5];
    const int*   acols = (const int*)d_in[6];
    const float* avals = (const float*)d_in[7];
    const float* Wq = (const float*)d_in[8];  const float* bq = (const float*)d_in[9];
    const float* Wk = (const float*)d_in[10]; const float* bk = (const float*)d_in[11];
    const float* Wv = (const float*)d_in[12]; const float* bv = (const float*)d_in[13];
    float* out = (float*)d_out;
    float* ws  = (float*)d_ws;

    const int NE  = NN * EDIM;             // 393216
    const int NQK = NN * DQK;              // 1572864
    float* ego1 = ws;
    float* ego2 = ws + NE;
    float* Qm   = ws + 2 * NE;
    float* Qa   = ws + 3 * NE;
    float* Ka   = Qa + NQK;
    float* Va   = Ka + NQK;
    float* pval = Va + NQK;
    int*   pidx = (int*)(pval + NN * SPLITS * KTOP);
    int*   idxf = pidx + NN * SPLITS * KTOP;
    float* PT   = ego1;                    // alias: ego1 dead after qm_mean

    // CSR scratch aliased over Qa (dead until qkv_gemm)
    int* csr     = (int*)Qa;
    int* cnt_n   = csr;
    int* cnt_a   = csr + 6144;
    int* start_n = csr + 12288;            // 6145
    int* start_a = csr + 18433;            // 6145
    int* cur_n   = csr + 24578;
    int* cur_a   = csr + 30722;
    int2* cv_n   = (int2*)(csr + 36866);   // byte-offset divisible by 8
    int2* cv_a   = cv_n + NNZ;

    // 1. zero histograms (12288 ints = 3072 float4)
    zero_kernel<<<12, TPB, 0, stream>>>((float4*)cnt_n, 3072);
    // 2-4. build both CSRs
    hist_kernel<<<(2 * NNZ + TPB - 1) / TPB, TPB, 0, stream>>>(nrows, arows, cnt_n, cnt_a);
    scan_kernel<<<2, 1024, 0, stream>>>(cnt_n, cnt_a, start_n, start_a, cur_n, cur_a);
    scatter_kernel<<<(2 * NNZ + TPB - 1) / TPB, TPB, 0, stream>>>(nrows, ncols, nvals,
                                                                  arows, acols, avals,
                                                                  cur_n, cur_a, cv_n, cv_a);
    // 5. ego1 = A_norm @ ego0
    spmm_csr_emb_kernel<<<NN / 4, TPB, 0, stream>>>(start_n, cv_n, user, item, ego1);
    // 6. ego2 = A_norm @ ego1
    spmm_csr_kernel<<<NN / 4, TPB, 0, stream>>>(start_n, cv_n, ego1, ego2);
    // 7. Qm = ego2 + 0.5*(A@ego2); out_mean = (ego0+ego1)/2
    qm_mean_kernel<<<NN / 4, TPB, 0, stream>>>(start_a, cv_a, ego2, ego1, user, item, Qm, out);
    // 8. PT = ego2^T  (overwrites ego1)
    transpose_kernel<<<NN / 64, TPB, 0, stream>>>(ego2, PT);
    // 9. Q/K/V = ego2 @ W^T + b  (overwrites CSR scratch)
    qkv_gemm_kernel<<<dim3(NN / 64, DQK / 128, 3), TPB, 0, stream>>>(ego2, Wq, bq, Wk, bk, Wv, bv,
                                                                     Qa, Ka, Va);
    // 10-11. top-5 of Qm·ego2^T
    topk_partial_kernel<<<dim3(NN / 128, SPLITS), TPB, 0, stream>>>(Qm, PT, pval, pidx);
    topk_final_kernel<<<NN / TPB, TPB, 0, stream>>>(pval, pidx, idxf);
    // 12. attention epilogue
    attn_kernel<<<NN / 4, TPB, 0, stream>>>(Qa, Ka, Va, idxf, out + NE);
}